// Round 8
// baseline (177.194 us; speedup 1.0000x reference)
//
#include <hip/hip_runtime.h>
#include <stdint.h>

// Problem constants (from reference)
#define N_NODES 50000
#define DEG     32
#define IN_DIM  256
#define K1      512   // 2*IN_DIM
#define HID     256
#define OUT_DIM 128

// fp8 gather tiling
#define NCHUNK  4
#define CDIM    64                          // dims per chunk (64 B fp8 per node-chunk)
#define SLICE8  ((size_t)N_NODES * CDIM)    // bytes per chunk slice (3.2 MB)
#define GT      16                          // nodes per gather block

// GEMM tiling
#define MT     32                           // nodes per tile
#define NTILES ((N_NODES + MT - 1) / MT)    // 1563
#define GBLK   256                          // persistent blocks (1/CU)
#define CSTR   520    // combined LDS row stride, bf16 elems (1040 B)
#define HSTR   264    // h LDS row stride, bf16 elems (528 B)

typedef __bf16 bf16x8 __attribute__((ext_vector_type(8)));
typedef float  f32x4  __attribute__((ext_vector_type(4)));
typedef float  f32x2  __attribute__((ext_vector_type(2)));

#define PIN(x) asm volatile("" : "+v"(x))

__device__ __forceinline__ unsigned short f2bf(float f) {
    union { float f; unsigned u; } v; v.f = f;
    unsigned r = v.u + 0x7fffu + ((v.u >> 16) & 1u);  // RNE (inputs finite)
    return (unsigned short)(r >> 16);
}
__device__ __forceinline__ int clampN(int v) {
    return v < 0 ? 0 : (v >= N_NODES ? N_NODES - 1 : v);
}
__device__ __forceinline__ void async_copy16(const void* g, void* l) {
    __builtin_amdgcn_global_load_lds(
        (const __attribute__((address_space(1))) void*)g,
        (__attribute__((address_space(3))) void*)l, 16, 0, 0);
}

// ---------------- merged prep: feat->bf16 + fp8 tiled; W1/W2->bf16; nbr->u16 ----------------
#define FEAT_BLKS ((N_NODES + 7) / 8)   // 6250
__global__ __launch_bounds__(256)
void prep_all(const float* __restrict__ feat,
              const float* __restrict__ W1, const float* __restrict__ W2,
              const int*   __restrict__ nbr,
              unsigned short* __restrict__ featb,   // [N,256] bf16
              unsigned char*  __restrict__ featF8,  // [4][N][64] fp8 e4m3
              unsigned short* __restrict__ W1b, unsigned short* __restrict__ W2b,
              unsigned short* __restrict__ nbr16)
{
    const int t = threadIdx.x;
    if (blockIdx.x < FEAT_BLKS) {
        const int node = blockIdx.x * 8 + (t >> 5);  // 8 nodes/block
        const int seg  = t & 31;                     // dims seg*8 .. seg*8+7
        if (node < N_NODES) {
            const float4* src = (const float4*)(feat + (size_t)node * IN_DIM + seg * 8);
            float4 f0 = src[0], f1 = src[1];
            ushort4 o0, o1;
            o0.x = f2bf(f0.x); o0.y = f2bf(f0.y); o0.z = f2bf(f0.z); o0.w = f2bf(f0.w);
            o1.x = f2bf(f1.x); o1.y = f2bf(f1.y); o1.z = f2bf(f1.z); o1.w = f2bf(f1.w);
            unsigned short* db = featb + (size_t)node * IN_DIM + seg * 8;
            *(ushort4*)db       = o0;
            *(ushort4*)(db + 4) = o1;
            int u0 = 0, u1 = 0;
            u0 = __builtin_amdgcn_cvt_pk_fp8_f32(f0.x, f0.y, u0, false);
            u0 = __builtin_amdgcn_cvt_pk_fp8_f32(f0.z, f0.w, u0, true);
            u1 = __builtin_amdgcn_cvt_pk_fp8_f32(f1.x, f1.y, u1, false);
            u1 = __builtin_amdgcn_cvt_pk_fp8_f32(f1.z, f1.w, u1, true);
            const int c   = seg >> 3;
            const int off = (seg & 7) * 8;
            unsigned char* d8 = featF8 + (size_t)c * SLICE8 + (size_t)node * CDIM + off;
            ((int*)d8)[0] = u0;
            ((int*)d8)[1] = u1;
        }
    } else {
        const int bid = blockIdx.x - FEAT_BLKS;           // 0..255
        const int stride = 256 * 256 * 4;
        const int tid4 = (bid * 256 + t) * 4;
        for (int i = tid4; i < HID * K1; i += stride) {
            float4 f = *(const float4*)(W1 + i);
            ushort4 o; o.x = f2bf(f.x); o.y = f2bf(f.y); o.z = f2bf(f.z); o.w = f2bf(f.w);
            *(ushort4*)(W1b + i) = o;
        }
        for (int i = tid4; i < OUT_DIM * HID; i += stride) {
            float4 f = *(const float4*)(W2 + i);
            ushort4 o; o.x = f2bf(f.x); o.y = f2bf(f.y); o.z = f2bf(f.z); o.w = f2bf(f.w);
            *(ushort4*)(W2b + i) = o;
        }
        for (int i = tid4; i < N_NODES * DEG; i += stride) {
            int4 v = *(const int4*)(nbr + i);
            ushort4 o;
            o.x = (unsigned short)clampN(v.x); o.y = (unsigned short)clampN(v.y);
            o.z = (unsigned short)clampN(v.z); o.w = (unsigned short)clampN(v.w);
            *(ushort4*)(nbr16 + i) = o;
        }
    }
}

// ---------------- gather + mean: fp8 slices, 8 B/lane, 128-thread blocks ----------------
// 8 lanes per node, each lane covers 8 dims (8 B). Per wave-load: 8 rows x 64 B.
__global__ __launch_bounds__(128)
void gather_mean_fp8(const unsigned char*  __restrict__ featF8,
                     const unsigned short* __restrict__ nbr16,
                     unsigned short*       __restrict__ meanb)  // [N,256] bf16
{
    __shared__ unsigned short sIdx[GT * DEG];  // 512 u16 = 1 KB
    const int tid  = threadIdx.x;              // 0..127
    const int c    = blockIdx.y;
    const int base = blockIdx.x * GT;          // N % GT == 0: no tail

    *(ushort4*)(sIdx + tid * 4) =
        *(const ushort4*)(nbr16 + (size_t)base * DEG + tid * 4);
    __syncthreads();

    const unsigned char* slice = featF8 + (size_t)c * SLICE8;
    const int grp = tid >> 3;     // node slot 0..15
    const int ln  = tid & 7;      // dims 8*ln .. 8*ln+7 of the chunk
    const unsigned short* idxr = sIdx + grp * DEG;

    // all 32 8-B loads issued before any use: max memory-level parallelism
    uint2 vv[DEG];
    #pragma unroll
    for (int j = 0; j < DEG; ++j) {
        int nb = idxr[j];
        vv[j] = *(const uint2*)(slice + (size_t)nb * CDIM + ln * 8);
    }
    float s[8];
    #pragma unroll
    for (int k = 0; k < 8; ++k) s[k] = 0.f;
    #pragma unroll
    for (int j = 0; j < DEG; ++j) {
        f32x2 a = __builtin_amdgcn_cvt_pk_f32_fp8(vv[j].x, false);
        f32x2 b = __builtin_amdgcn_cvt_pk_f32_fp8(vv[j].x, true);
        f32x2 d = __builtin_amdgcn_cvt_pk_f32_fp8(vv[j].y, false);
        f32x2 e = __builtin_amdgcn_cvt_pk_f32_fp8(vv[j].y, true);
        s[0] += a[0]; s[1] += a[1]; s[2] += b[0]; s[3] += b[1];
        s[4] += d[0]; s[5] += d[1]; s[6] += e[0]; s[7] += e[1];
    }
    const float sc = 1.0f / 32.0f;
    ushort4 o0, o1;
    o0.x = f2bf(s[0] * sc); o0.y = f2bf(s[1] * sc);
    o0.z = f2bf(s[2] * sc); o0.w = f2bf(s[3] * sc);
    o1.x = f2bf(s[4] * sc); o1.y = f2bf(s[5] * sc);
    o1.z = f2bf(s[6] * sc); o1.w = f2bf(s[7] * sc);
    unsigned short* dst = meanb + (size_t)(base + grp) * IN_DIM + c * CDIM + ln * 8;
    *(ushort4*)dst       = o0;
    *(ushort4*)(dst + 4) = o1;
}

// ---------------- persistent GEMM: 1 barrier/tile pipeline, swapped-operand MFMA ----------------
// MFMA fragment layouts (measured, learn_hip m89/m91/m120):
//   A and B operands share the mapping [idx = lane&15][k = (lane>>4)*8 + j].
//   C/D: col(n) = lane&15, row(m) = (lane>>4)*4 + reg.
// We compute D = W-frag (A) x node-frag (B): lane then holds, for NODE = lane&15,
// the 4 consecutive W-rows (h-cols / out-cols) q*4+g  ->  vectorized sH / out writes.
__global__ __launch_bounds__(512, 2)
void sage_gemm_pipe(const unsigned short* __restrict__ featb,  // [N,256] bf16
                    const unsigned short* __restrict__ meanb,  // [N,256] bf16
                    const unsigned short* __restrict__ W1b,    // [256,512] bf16
                    const float*          __restrict__ b1,
                    const unsigned short* __restrict__ W2b,    // [128,256] bf16
                    const float*          __restrict__ b2,
                    float*                __restrict__ out)    // [N,128]
{
    __shared__ __align__(16) unsigned short sC[2][MT * CSTR];  // 2 x 33280 B
    __shared__ __align__(16) unsigned short sH[2][MT * HSTR];  // 2 x 16896 B (100352 total)

    const int tid  = threadIdx.x;
    const int lane = tid & 63;
    const int wave = tid >> 6;     // 0..7
    const int r    = lane & 15;
    const int q    = lane >> 4;

    // ---- one-time: W fragments into registers, pinned against remat ----
    bf16x8 w1f[2][16];   // h-cols wave*32 + nt*16 + r (as A-operand rows)
    #pragma unroll
    for (int nt = 0; nt < 2; ++nt) {
        const size_t nrow = (size_t)(wave * 32 + nt * 16 + r) * K1;
        #pragma unroll
        for (int kk = 0; kk < 16; ++kk) {
            w1f[nt][kk] = *(const bf16x8*)(W1b + nrow + kk * 32 + q * 8);
            PIN(w1f[nt][kk]);
        }
    }
    bf16x8 w2f[8];       // out-col wave*16 + r
    {
        const size_t orow = (size_t)(wave * 16 + r) * HID;
        #pragma unroll
        for (int kk = 0; kk < 8; ++kk) {
            w2f[kk] = *(const bf16x8*)(W2b + orow + kk * 32 + q * 8);
            PIN(w2f[kk]);
        }
    }
    const float4 bias1v0 = *(const float4*)(b1 + wave * 32 + q * 4);
    const float4 bias1v1 = *(const float4*)(b1 + wave * 32 + 16 + q * 4);
    const float4 bias2v  = *(const float4*)(b2 + wave * 16 + q * 4);

    auto stage = [&](int tile, int buf) {
        const int tbase = tile * MT;
        #pragma unroll
        for (int j = 0; j < 4; ++j) {
            const int i = wave * 4 + j;           // row 0..31 (wave-uniform)
            int node = tbase + i;
            if (node >= N_NODES) node = N_NODES - 1;
            const unsigned short* g = (lane < 32)
                ? featb + (size_t)node * IN_DIM + lane * 8
                : meanb + (size_t)node * IN_DIM + (lane - 32) * 8;
            async_copy16(g, &sC[buf][i * CSTR]);
        }
    };

    auto phase2 = [&](int cbuf, int hbuf) {
        f32x4 acc[2][2];
        #pragma unroll
        for (int mt = 0; mt < 2; ++mt)
            #pragma unroll
            for (int nt = 0; nt < 2; ++nt)
                acc[mt][nt] = (f32x4){0.f, 0.f, 0.f, 0.f};
        #pragma unroll
        for (int kk = 0; kk < 16; ++kk) {
            bf16x8 a0 = *(const bf16x8*)(&sC[cbuf][r * CSTR + kk * 32 + q * 8]);
            bf16x8 a1 = *(const bf16x8*)(&sC[cbuf][(16 + r) * CSTR + kk * 32 + q * 8]);
            acc[0][0] = __builtin_amdgcn_mfma_f32_16x16x32_bf16(w1f[0][kk], a0, acc[0][0], 0, 0, 0);
            acc[1][0] = __builtin_amdgcn_mfma_f32_16x16x32_bf16(w1f[0][kk], a1, acc[1][0], 0, 0, 0);
            acc[0][1] = __builtin_amdgcn_mfma_f32_16x16x32_bf16(w1f[1][kk], a0, acc[0][1], 0, 0, 0);
            acc[1][1] = __builtin_amdgcn_mfma_f32_16x16x32_bf16(w1f[1][kk], a1, acc[1][1], 0, 0, 0);
        }
        // lane holds h[node = mt*16+r][hcol = wave*32+nt*16+q*4+g] -> ushort4 writes
        #pragma unroll
        for (int nt = 0; nt < 2; ++nt) {
            const float4 bias = nt ? bias1v1 : bias1v0;
            #pragma unroll
            for (int mt = 0; mt < 2; ++mt) {
                float v0 = acc[mt][nt][0] + bias.x;
                float v1 = acc[mt][nt][1] + bias.y;
                float v2 = acc[mt][nt][2] + bias.z;
                float v3 = acc[mt][nt][3] + bias.w;
                ushort4 o;
                o.x = f2bf(v0 > 0.f ? v0 : 0.f);
                o.y = f2bf(v1 > 0.f ? v1 : 0.f);
                o.z = f2bf(v2 > 0.f ? v2 : 0.f);
                o.w = f2bf(v3 > 0.f ? v3 : 0.f);
                *(ushort4*)(&sH[hbuf][(mt * 16 + r) * HSTR + wave * 32 + nt * 16 + q * 4]) = o;
            }
        }
    };

    auto phase3 = [&](int hbuf, int pbase) {
        f32x4 acc3[2];
        acc3[0] = (f32x4){0.f, 0.f, 0.f, 0.f};
        acc3[1] = (f32x4){0.f, 0.f, 0.f, 0.f};
        #pragma unroll
        for (int kk = 0; kk < 8; ++kk) {
            bf16x8 h0 = *(const bf16x8*)(&sH[hbuf][r * HSTR + kk * 32 + q * 8]);
            bf16x8 h1 = *(const bf16x8*)(&sH[hbuf][(16 + r) * HSTR + kk * 32 + q * 8]);
            acc3[0] = __builtin_amdgcn_mfma_f32_16x16x32_bf16(w2f[kk], h0, acc3[0], 0, 0, 0);
            acc3[1] = __builtin_amdgcn_mfma_f32_16x16x32_bf16(w2f[kk], h1, acc3[1], 0, 0, 0);
        }
        // lane holds out[node = mt*16+r][ocol = wave*16+q*4+g] -> float4 stores
        #pragma unroll
        for (int mt = 0; mt < 2; ++mt) {
            const int node = pbase + mt * 16 + r;
            if (node < N_NODES) {
                float4 v;
                v.x = acc3[mt][0] + bias2v.x; v.x = v.x > 0.f ? v.x : 0.f;
                v.y = acc3[mt][1] + bias2v.y; v.y = v.y > 0.f ? v.y : 0.f;
                v.z = acc3[mt][2] + bias2v.z; v.z = v.z > 0.f ? v.z : 0.f;
                v.w = acc3[mt][3] + bias2v.w; v.w = v.w > 0.f ? v.w : 0.f;
                *(float4*)(out + (size_t)node * OUT_DIM + wave * 16 + q * 4) = v;
            }
        }
    };

    // ---- pipelined persistent loop: ONE barrier per tile ----
    int tile = blockIdx.x;
    int buf = 0, hb = 0;
    int prev_base = -1;
    if (tile < NTILES) stage(tile, 0);

    for (; tile < NTILES; tile += GBLK) {
        __syncthreads();   // drains prefetch (sC[buf] ready) + prev sH writes
        if (tile + GBLK < NTILES) stage(tile + GBLK, buf ^ 1);  // overlaps both phases
        phase2(buf, hb);                    // sC[buf] -> sH[hb]
        if (prev_base >= 0) phase3(hb ^ 1, prev_base);
        prev_base = tile * MT;
        buf ^= 1; hb ^= 1;
    }
    __syncthreads();
    if (prev_base >= 0) phase3(hb ^ 1, prev_base);   // drain last tile
}

// ---------------- naive fp32 fallback (only if ws too small) ----------------
__global__ __launch_bounds__(256)
void sage_naive(const float* __restrict__ feat, const int* __restrict__ nbr,
                const float* __restrict__ W1, const float* __restrict__ b1,
                const float* __restrict__ W2, const float* __restrict__ b2,
                float* __restrict__ out) {
    __shared__ float comb[K1];
    __shared__ float h[HID];
    const int node = blockIdx.x;
    const int t = threadIdx.x;  // 256
    comb[t] = feat[(size_t)node * IN_DIM + t];
    float acc = 0.f;
    for (int d = 0; d < DEG; ++d) {
        int nb = clampN(nbr[node * DEG + d]);
        acc += feat[(size_t)nb * IN_DIM + t];
    }
    comb[IN_DIM + t] = acc * (1.0f / 32.0f);
    __syncthreads();
    float s = b1[t];
    for (int k = 0; k < K1; ++k) s += comb[k] * W1[(size_t)t * K1 + k];
    h[t] = s > 0.f ? s : 0.f;
    __syncthreads();
    if (t < OUT_DIM) {
        float s2 = b2[t];
        for (int k = 0; k < HID; ++k) s2 += h[k] * W2[(size_t)t * HID + k];
        out[(size_t)node * OUT_DIM + t] = s2 > 0.f ? s2 : 0.f;
    }
}

extern "C" void kernel_launch(void* const* d_in, const int* in_sizes, int n_in,
                              void* d_out, int out_size, void* d_ws, size_t ws_size,
                              hipStream_t stream) {
    const float* feat = (const float*)d_in[0];
    const int*   nbr  = (const int*)d_in[1];
    const float* W1   = (const float*)d_in[2];
    const float* b1   = (const float*)d_in[3];
    const float* W2   = (const float*)d_in[4];
    const float* b2   = (const float*)d_in[5];
    float* out = (float*)d_out;

    const size_t feat_elems = (size_t)N_NODES * IN_DIM;   // 12.8M
    const size_t w1_elems   = (size_t)HID * K1;
    const size_t w2_elems   = (size_t)OUT_DIM * HID;
    const size_t mean_elems = (size_t)N_NODES * IN_DIM;
    const size_t idx_elems  = (size_t)N_NODES * DEG;
    const size_t u16_elems  = feat_elems + w1_elems + w2_elems + mean_elems + idx_elems;
    const size_t need = u16_elems * sizeof(unsigned short)
                      + (size_t)NCHUNK * SLICE8;          // ~67.6 MB

    if (ws_size >= need) {
        unsigned short* featb  = (unsigned short*)d_ws;
        unsigned short* W1b    = featb + feat_elems;
        unsigned short* W2b    = W1b + w1_elems;
        unsigned short* meanb  = W2b + w2_elems;
        unsigned short* nbr16  = meanb + mean_elems;
        unsigned char*  featF8 = (unsigned char*)(nbr16 + idx_elems);

        prep_all<<<FEAT_BLKS + 256, 256, 0, stream>>>(feat, W1, W2, nbr,
                                                      featb, featF8, W1b, W2b, nbr16);
        gather_mean_fp8<<<dim3(N_NODES / GT, NCHUNK), 128, 0, stream>>>(featF8, nbr16, meanb);
        sage_gemm_pipe<<<GBLK, 512, 0, stream>>>(featb, meanb, W1b, b1, W2b, b2, out);
    } else {
        sage_naive<<<N_NODES, 256, 0, stream>>>(feat, nbr, W1, b1, W2, b2, out);
    }
}